// Round 6
// baseline (35.201 us; speedup 1.0000x reference)
//
#include <hip/hip_runtime.h>
#include <math.h>

#define BLOCK 256
#define WPB   (BLOCK / 64)     // 4 waves per block
#define K     2048
#define ROWS_PER_WAVE 4        // processed as 2 clustered pairs
#define GRID  1024             // 16384 rows / (4 waves * 4 rows)

__device__ __forceinline__ float sq4(float4 v) {
    return v.x * v.x + v.y * v.y + v.z * v.z + v.w * v.w;
}

// Single fused kernel. Phase-1 body identical to R4. Finalize fused via a
// contention-safe last-block protocol:
//   - partials published with device-scope atomicExch (RMW -> coherence point)
//   - wave-local s_waitcnt vmcnt(0) on the returned value orders publish
//     before the arrival-counter increment (no __threadfence cache drain)
//   - counter is memset to 0 each call (R5 bug: poisoned counter made the
//     mod-trigger fire at the 342nd arrival, not the 1024th)
//   - last block reads partials via atomicAdd(+0.0f) so reads come from the
//     coherence point, immune to stale per-XCD L2.
__global__ __launch_bounds__(BLOCK) void row_ssq_fused(
    const float* __restrict__ d, float* __restrict__ partials,
    unsigned int* __restrict__ cnt, float* __restrict__ out) {
    const int wave = threadIdx.x >> 6;
    const int lane = threadIdx.x & 63;
    const int base = (blockIdx.x * WPB + wave) * ROWS_PER_WAVE;

    float acc = 0.0f;
#pragma unroll
    for (int pair = 0; pair < 2; ++pair) {
        const float4* __restrict__ pa =
            reinterpret_cast<const float4*>(d + (size_t)(base + 2 * pair) * K);
        const float4* __restrict__ pb =
            reinterpret_cast<const float4*>(d + (size_t)(base + 2 * pair + 1) * K);
        float4 a0 = pa[lane + 64 * 0], b0 = pb[lane + 64 * 0];
        float4 a1 = pa[lane + 64 * 1], b1 = pb[lane + 64 * 1];
        float4 a2 = pa[lane + 64 * 2], b2 = pb[lane + 64 * 2];
        float4 a3 = pa[lane + 64 * 3], b3 = pb[lane + 64 * 3];
        float4 a4 = pa[lane + 64 * 4], b4 = pb[lane + 64 * 4];
        float4 a5 = pa[lane + 64 * 5], b5 = pb[lane + 64 * 5];
        float4 a6 = pa[lane + 64 * 6], b6 = pb[lane + 64 * 6];
        float4 a7 = pa[lane + 64 * 7], b7 = pb[lane + 64 * 7];

        float sa = ((sq4(a0) + sq4(a1)) + (sq4(a2) + sq4(a3))) +
                   ((sq4(a4) + sq4(a5)) + (sq4(a6) + sq4(a7)));
        float sb = ((sq4(b0) + sq4(b1)) + (sq4(b2) + sq4(b3))) +
                   ((sq4(b4) + sq4(b5)) + (sq4(b6) + sq4(b7)));
#pragma unroll
        for (int off = 32; off >= 1; off >>= 1) {
            sa += __shfl_xor(sa, off);
            sb += __shfl_xor(sb, off);
        }
        float ta = sa - 1.0f, tb = sb - 1.0f;
        acc += ta * ta + tb * tb;
    }

    __shared__ float smem[WPB];
    __shared__ unsigned int s_last;
    if (lane == 0) smem[wave] = acc;
    __syncthreads();

    if (threadIdx.x == 0) {
        float b = smem[0] + smem[1] + smem[2] + smem[3];
        // Publish partial: device-scope RMW to the coherence point.
        float old = atomicExch(&partials[blockIdx.x], b);
        asm volatile("" :: "v"(old));  // keep return live -> vmcnt tracks it
        asm volatile("s_waitcnt vmcnt(0)" ::: "memory");  // publish complete
        unsigned int prev = atomicAdd(cnt, 1u);           // then arrive
        s_last = (prev == GRID - 1) ? 1u : 0u;            // counter reset by memset
    }
    __syncthreads();

    if (s_last != 0u && wave == 0) {
        // All 1023 other partials are complete at the coherence point.
        float t = 0.0f;
#pragma unroll
        for (int i = 0; i < GRID / 64; ++i)
            t += atomicAdd(&partials[lane + 64 * i], 0.0f);
#pragma unroll
        for (int off = 32; off >= 1; off >>= 1)
            t += __shfl_xor(t, off);
        if (lane == 0) out[0] = 0.001f * sqrtf(t);
    }
}

extern "C" void kernel_launch(void* const* d_in, const int* in_sizes, int n_in,
                              void* d_out, int out_size, void* d_ws, size_t ws_size,
                              hipStream_t stream) {
    const float* d = (const float*)d_in[0];
    float* out = (float*)d_out;
    float* partials = (float*)d_ws;                   // GRID floats
    unsigned int* cnt = (unsigned int*)((char*)d_ws + GRID * sizeof(float));

    hipMemsetAsync(cnt, 0, sizeof(unsigned int), stream);  // counter := 0
    row_ssq_fused<<<GRID, BLOCK, 0, stream>>>(d, partials, cnt, out);
}

// Round 7
// 33.112 us; speedup vs baseline: 1.0631x; 1.0631x over previous
//
#include <hip/hip_runtime.h>
#include <math.h>

#define BLOCK 1024             // 16 waves per block, 1 block per CU
#define WPB   (BLOCK / 64)     // 16
#define K     2048
#define ROWS_PER_WAVE 4        // 2 clustered pairs (same inner body as R4)
#define GRID  256              // 16384 rows / (16 waves * 4 rows)

__device__ __forceinline__ float sq4(float4 v) {
    return v.x * v.x + v.y * v.y + v.z * v.z + v.w * v.w;
}

// Phase 1: 1 block/CU. Each wave owns 4 adjacent rows as two clustered pairs
// (16 float4 loads in flight before first waitcnt). Plain partial store per
// block. No atomics, no fences (fusion lost twice: R2 -62us, R6 -7.5us).
__global__ __launch_bounds__(BLOCK) void row_ssq_kernel(
    const float* __restrict__ d, float* __restrict__ partials) {
    const int wave = threadIdx.x >> 6;
    const int lane = threadIdx.x & 63;
    const int base = (blockIdx.x * WPB + wave) * ROWS_PER_WAVE;

    float acc = 0.0f;
#pragma unroll
    for (int pair = 0; pair < 2; ++pair) {
        const float4* __restrict__ pa =
            reinterpret_cast<const float4*>(d + (size_t)(base + 2 * pair) * K);
        const float4* __restrict__ pb =
            reinterpret_cast<const float4*>(d + (size_t)(base + 2 * pair + 1) * K);
        float4 a0 = pa[lane + 64 * 0], b0 = pb[lane + 64 * 0];
        float4 a1 = pa[lane + 64 * 1], b1 = pb[lane + 64 * 1];
        float4 a2 = pa[lane + 64 * 2], b2 = pb[lane + 64 * 2];
        float4 a3 = pa[lane + 64 * 3], b3 = pb[lane + 64 * 3];
        float4 a4 = pa[lane + 64 * 4], b4 = pb[lane + 64 * 4];
        float4 a5 = pa[lane + 64 * 5], b5 = pb[lane + 64 * 5];
        float4 a6 = pa[lane + 64 * 6], b6 = pb[lane + 64 * 6];
        float4 a7 = pa[lane + 64 * 7], b7 = pb[lane + 64 * 7];

        float sa = ((sq4(a0) + sq4(a1)) + (sq4(a2) + sq4(a3))) +
                   ((sq4(a4) + sq4(a5)) + (sq4(a6) + sq4(a7)));
        float sb = ((sq4(b0) + sq4(b1)) + (sq4(b2) + sq4(b3))) +
                   ((sq4(b4) + sq4(b5)) + (sq4(b6) + sq4(b7)));
#pragma unroll
        for (int off = 32; off >= 1; off >>= 1) {
            sa += __shfl_xor(sa, off);
            sb += __shfl_xor(sb, off);
        }
        float ta = sa - 1.0f, tb = sb - 1.0f;
        acc += ta * ta + tb * tb;
    }

    __shared__ float smem[WPB];
    if (lane == 0) smem[wave] = acc;
    __syncthreads();
    if (threadIdx.x == 0) {
        float b = 0.0f;
#pragma unroll
        for (int i = 0; i < WPB; ++i) b += smem[i];
        partials[blockIdx.x] = b;
    }
}

// Phase 2: one wave, 256 partials = exactly 1 float4 per lane.
__global__ __launch_bounds__(64) void finalize_kernel(
    const float* __restrict__ partials, float* __restrict__ out) {
    const int lane = threadIdx.x;
    float4 v = reinterpret_cast<const float4*>(partials)[lane];
    float acc = (v.x + v.y) + (v.z + v.w);
#pragma unroll
    for (int off = 32; off >= 1; off >>= 1)
        acc += __shfl_xor(acc, off);
    if (lane == 0) out[0] = 0.001f * sqrtf(acc);
}

extern "C" void kernel_launch(void* const* d_in, const int* in_sizes, int n_in,
                              void* d_out, int out_size, void* d_ws, size_t ws_size,
                              hipStream_t stream) {
    const float* d = (const float*)d_in[0];
    float* out = (float*)d_out;
    float* partials = (float*)d_ws;   // GRID floats

    row_ssq_kernel<<<GRID, BLOCK, 0, stream>>>(d, partials);
    finalize_kernel<<<1, 64, 0, stream>>>(partials, out);
}

// Round 8
// 25.217 us; speedup vs baseline: 1.3959x; 1.3131x over previous
//
#include <hip/hip_runtime.h>
#include <math.h>

#define BLOCK 256
#define WPB   (BLOCK / 64)     // 4 waves per block
#define K     2048
#define ROWS_PER_WAVE 4        // 2 clustered pairs (R4 structure, best: 27.7us)
#define GRID  1024             // 16384 rows / (4 waves * 4 rows)

typedef float f32x4 __attribute__((ext_vector_type(4)));

__device__ __forceinline__ float sq4(f32x4 v) {
    return v.x * v.x + v.y * v.y + v.z * v.z + v.w * v.w;
}

// Non-temporal dwordx4 load: nt bit skips L1/L2 allocation (streaming read,
// zero intra-call reuse). HIP float4 is a struct -> use ext_vector_type.
__device__ __forceinline__ f32x4 ldnt(const f32x4* p) {
    return __builtin_nontemporal_load(p);
}

// Phase 1: R4 geometry (1024 blk x 256 thr, 4 adjacent rows/wave as two
// clustered pairs of 16 in-flight loads), with nt loads. Plain partial store.
__global__ __launch_bounds__(BLOCK) void row_ssq_kernel(
    const float* __restrict__ d, float* __restrict__ partials) {
    const int wave = threadIdx.x >> 6;
    const int lane = threadIdx.x & 63;
    const int base = (blockIdx.x * WPB + wave) * ROWS_PER_WAVE;

    float acc = 0.0f;
#pragma unroll
    for (int pair = 0; pair < 2; ++pair) {
        const f32x4* __restrict__ pa =
            reinterpret_cast<const f32x4*>(d + (size_t)(base + 2 * pair) * K);
        const f32x4* __restrict__ pb =
            reinterpret_cast<const f32x4*>(d + (size_t)(base + 2 * pair + 1) * K);
        f32x4 a0 = ldnt(pa + lane + 64 * 0), b0 = ldnt(pb + lane + 64 * 0);
        f32x4 a1 = ldnt(pa + lane + 64 * 1), b1 = ldnt(pb + lane + 64 * 1);
        f32x4 a2 = ldnt(pa + lane + 64 * 2), b2 = ldnt(pb + lane + 64 * 2);
        f32x4 a3 = ldnt(pa + lane + 64 * 3), b3 = ldnt(pb + lane + 64 * 3);
        f32x4 a4 = ldnt(pa + lane + 64 * 4), b4 = ldnt(pb + lane + 64 * 4);
        f32x4 a5 = ldnt(pa + lane + 64 * 5), b5 = ldnt(pb + lane + 64 * 5);
        f32x4 a6 = ldnt(pa + lane + 64 * 6), b6 = ldnt(pb + lane + 64 * 6);
        f32x4 a7 = ldnt(pa + lane + 64 * 7), b7 = ldnt(pb + lane + 64 * 7);

        float sa = ((sq4(a0) + sq4(a1)) + (sq4(a2) + sq4(a3))) +
                   ((sq4(a4) + sq4(a5)) + (sq4(a6) + sq4(a7)));
        float sb = ((sq4(b0) + sq4(b1)) + (sq4(b2) + sq4(b3))) +
                   ((sq4(b4) + sq4(b5)) + (sq4(b6) + sq4(b7)));
#pragma unroll
        for (int off = 32; off >= 1; off >>= 1) {
            sa += __shfl_xor(sa, off);
            sb += __shfl_xor(sb, off);
        }
        float ta = sa - 1.0f, tb = sb - 1.0f;
        acc += ta * ta + tb * tb;
    }

    __shared__ float smem[WPB];
    if (lane == 0) smem[wave] = acc;
    __syncthreads();
    if (threadIdx.x == 0)
        partials[blockIdx.x] = smem[0] + smem[1] + smem[2] + smem[3];
}

// Phase 2: one wave, 1024 partials = 4 float4 per lane.
__global__ __launch_bounds__(64) void finalize_kernel(
    const float* __restrict__ partials, float* __restrict__ out) {
    const int lane = threadIdx.x;
    const f32x4* __restrict__ p = reinterpret_cast<const f32x4*>(partials);
    f32x4 v0 = p[lane + 64 * 0];
    f32x4 v1 = p[lane + 64 * 1];
    f32x4 v2 = p[lane + 64 * 2];
    f32x4 v3 = p[lane + 64 * 3];
    float acc = ((v0.x + v0.y + v0.z + v0.w) + (v1.x + v1.y + v1.z + v1.w)) +
                ((v2.x + v2.y + v2.z + v2.w) + (v3.x + v3.y + v3.z + v3.w));
#pragma unroll
    for (int off = 32; off >= 1; off >>= 1)
        acc += __shfl_xor(acc, off);
    if (lane == 0) out[0] = 0.001f * sqrtf(acc);
}

extern "C" void kernel_launch(void* const* d_in, const int* in_sizes, int n_in,
                              void* d_out, int out_size, void* d_ws, size_t ws_size,
                              hipStream_t stream) {
    const float* d = (const float*)d_in[0];
    float* out = (float*)d_out;
    float* partials = (float*)d_ws;   // GRID floats

    row_ssq_kernel<<<GRID, BLOCK, 0, stream>>>(d, partials);
    finalize_kernel<<<1, 64, 0, stream>>>(partials, out);
}